// Round 10
// baseline (673.988 us; speedup 1.0000x reference)
//
#include <hip/hip_runtime.h>
#include <hip/hip_bf16.h>

#define N_NODES 50000
#define N_EDGES 800000
#define H 64
#define ED 32
#define LAYERS 3
#define NGRAPH 256
#define OUTD 32
#define SCALE 0.125f
#define NCAT 42

// bucketed counting sort for CSR build (no global atomics anywhere)
#define BNODES 128                                  // nodes per bucket (dst >> 7)
#define NBUCK 391                                   // ceil(50000/128)
#define NB_HISTB 256                                // histogram / scatter blocks
#define EPB (N_EDGES / NB_HISTB)                    // 3125 edges per block

// fused front-end virtual block ranges
#define FB_HIST 256
#define FB_TE   8
#define FB_GB   2
#define FB_WB   192                                 // 3*16384 bf16 weight fragments / 256
#define FB_TAB  NCAT                                // layer-0 qkv table, 1 block per category
#define NB_FRONT (FB_HIST + FB_TE + FB_GB + FB_WB + FB_TAB)

#define NB_SCAN   98                                // 391 buckets / 4 per block
#define NB_AGG    3125                              // 50000 dsts / 16
#define PKCAP     768                               // staged packets per block (avg 256)

typedef __attribute__((ext_vector_type(8))) short bf16x8;
typedef __attribute__((ext_vector_type(4))) float f32x4;
typedef unsigned short ushort_t;

// fp32 -> bf16 round-to-nearest-even
__device__ __forceinline__ unsigned f2bf(float f) {
    unsigned u = __float_as_uint(f);
    return (u + 0x7FFFu + ((u >> 16) & 1u)) >> 16;
}

// 16-lane all-reduce sum via DPP (VALU only, no LDS pipe).
__device__ __forceinline__ float radd16(float x) {
    x += __int_as_float(__builtin_amdgcn_update_dpp(0, __float_as_int(x), 0xB1, 0xF, 0xF, true));   // quad_perm 1,0,3,2
    x += __int_as_float(__builtin_amdgcn_update_dpp(0, __float_as_int(x), 0x4E, 0xF, 0xF, true));   // quad_perm 2,3,0,1
    x += __int_as_float(__builtin_amdgcn_update_dpp(0, __float_as_int(x), 0x124, 0xF, 0xF, true));  // row_ror:4
    x += __int_as_float(__builtin_amdgcn_update_dpp(0, __float_as_int(x), 0x128, 0xF, 0xF, true));  // row_ror:8
    return x;
}

// shared prologue: exclusive scan of 391 bucket totals -> bst[] in LDS
__device__ __forceinline__ void build_bstart(const int* __restrict__ tot,
                                             int* bst, int* part, int t) {
    int u0 = t * 2, u1 = t * 2 + 1;
    int a0 = (u0 < NBUCK) ? tot[u0] : 0;
    int a1 = (u1 < NBUCK) ? tot[u1] : 0;
    part[t] = a0 + a1;
    __syncthreads();
    for (int off = 1; off < 256; off <<= 1) {
        int add = (t >= off) ? part[t - off] : 0;
        __syncthreads();
        part[t] += add;
        __syncthreads();
    }
    int excl = part[t] - (a0 + a1);
    if (u0 < NBUCK) bst[u0] = excl;
    if (u1 < NBUCK) bst[u1] = excl + a0;
    if (t == 0) bst[NBUCK] = N_EDGES;
    __syncthreads();
}

__device__ __forceinline__ int bsearch_batch(const int* __restrict__ batch, int g) {
    int lo = 0, hi = N_NODES;
    while (lo < hi) {
        int mid = (lo + hi) >> 1;
        if (batch[mid] < g) lo = mid + 1; else hi = mid;
    }
    return lo;
}

// ---------------- fused front end: hist | te | gbounds+gcnt | weights | layer0-table ---
__global__ __launch_bounds__(256) void k_front(
    const int* __restrict__ x, const float* __restrict__ node_emb,
    const float* __restrict__ edge_emb, const float* __restrict__ We, float* __restrict__ te,
    const int* __restrict__ ei, int* __restrict__ hist,
    const int* __restrict__ batch, int* __restrict__ gs, int* __restrict__ gcnt,
    const float* __restrict__ Wq, const float* __restrict__ Wk,
    const float* __restrict__ Wv, const float* __restrict__ Wsk,
    const float* __restrict__ bq, const float* __restrict__ bk,
    const float* __restrict__ bv, const float* __restrict__ bsk,
    ushort_t* __restrict__ wb16,
    unsigned* __restrict__ tqs, unsigned* __restrict__ tkv)
{
    __shared__ int lh[NBUCK];
    __shared__ float tb[4][64];
    int b = blockIdx.x, t = threadIdx.x;
    if (b < FB_HIST) {
        // per-block bucket histogram in LDS; transposed writeback hist[bucket][block]
        for (int i = t; i < NBUCK; i += 256) lh[i] = 0;
        __syncthreads();
        const int* dstp = ei + N_EDGES + b * EPB;
        for (int i = t; i < EPB; i += 256)
            atomicAdd(&lh[dstp[i] >> 7], 1);
        __syncthreads();
        for (int i = t; i < NBUCK; i += 256) hist[i * NB_HISTB + b] = lh[i];
    } else if (b < FB_HIST + FB_TE) {
        int i = (b - FB_HIST) * 256 + t;
        if (i < LAYERS * 10 * H) {
            int c = i & 63;
            int cat = (i >> 6) % 10;
            int l = i / (10 * H);
            float acc = 0.f;
            for (int d = 0; d < ED; d++)
                acc += edge_emb[cat * ED + d] * We[((size_t)l * ED + d) * H + c];
            te[i] = acc;
        }
    } else if (b < FB_HIST + FB_TE + FB_GB) {
        int g = (b - FB_HIST - FB_TE) * 256 + t;
        if (g <= NGRAPH) {
            int lo = bsearch_batch(batch, g);
            gs[g] = lo;
            if (g < NGRAPH) {
                int hi2 = bsearch_batch(batch, g + 1);
                // #16-node tiles intersecting [lo, hi2): exact, incl. empty-graph cases
                gcnt[g] = ((hi2 - 1) >> 4) - (lo >> 4) + 1;
            }
        }
    } else if (b < FB_HIST + FB_TE + FB_GB + FB_WB) {
        // chunk-major weight layout: wb16[l][c_id][r][j]  (c_id = kb*4+quad, r = ct*16+n16)
        int g = (b - FB_HIST - FB_TE - FB_GB) * 256 + t;   // < 49152
        int l = g >> 14;
        int rem = g & 16383;
        int c_id = rem >> 11;
        int rr = (rem >> 3) & 255;
        int j = rem & 7;
        int mat = rr >> 6, n = rr & 63;
        int k = ((c_id >> 2) << 5) + ((c_id & 3) << 3) + j;
        const float* Wm = (mat == 0) ? Wq : (mat == 1) ? Wk : (mat == 2) ? Wv : Wsk;
        wb16[g] = (ushort_t)f2bf(Wm[(size_t)l * 4096 + k * 64 + n]);
    } else {
        // layer-0 qkv table: one block per node category, fp32 matvec (exact)
        int cat = b - (FB_HIST + FB_TE + FB_GB + FB_WB);
        int mat = t >> 6, c = t & 63;
        const float* Wm = (mat == 0) ? Wq : (mat == 1) ? Wk : (mat == 2) ? Wv : Wsk;
        const float* bm = (mat == 0) ? bq : (mat == 1) ? bk : (mat == 2) ? bv : bsk;
        float acc = bm[c];
        for (int k = 0; k < H; k++)
            acc += node_emb[cat * H + k] * Wm[k * 64 + c];
        tb[mat][c] = acc;
        __syncthreads();
        if (t < 64) {
            tqs[cat * 64 + t] = f2bf(tb[0][t]) | (f2bf(tb[3][t]) << 16);   // q | skip
            tkv[cat * 64 + t] = f2bf(tb[2][t]) | (f2bf(tb[1][t]) << 16);   // v | k
        }
    }
}

// ---------------- per-bucket block-prefix scan (in-place) ----------------
__global__ __launch_bounds__(256) void k_scan(int* __restrict__ hist, int* __restrict__ tot)
{
    __shared__ int sv[256];
    int sb = blockIdx.x, t = threadIdx.x;
    for (int r = 0; r < 4; r++) {
        int u = sb * 4 + r;
        if (u < NBUCK) {
            int v = hist[u * NB_HISTB + t];
            sv[t] = v;
            __syncthreads();
            for (int off = 1; off < 256; off <<= 1) {
                int add = (t >= off) ? sv[t - off] : 0;
                __syncthreads();
                sv[t] += add;
                __syncthreads();
            }
            int incl = sv[t];
            hist[u * NB_HISTB + t] = incl - v;   // exclusive prefix, in place
            if (t == 255) tot[u] = incl;
            __syncthreads();
        }
    }
}

// ---------------- scatter: rank via LDS atomics against per-block cursors -------------
// packet: src(0..15) | catx(16..24) where catx = cat*42 + x[src] | (dst&127)(25..31)
__global__ __launch_bounds__(256) void k_scatter(
    const int* __restrict__ ei, const int* __restrict__ ea, const int* __restrict__ x,
    const int* __restrict__ hist, const int* __restrict__ tot,
    int* __restrict__ pmid)
{
    __shared__ int bst[NBUCK + 1];
    __shared__ int part[256];
    __shared__ int curS[NBUCK];
    int b = blockIdx.x, t = threadIdx.x;
    build_bstart(tot, bst, part, t);
    for (int u = t; u < NBUCK; u += 256)
        curS[u] = bst[u] + hist[u * NB_HISTB + b];
    __syncthreads();
    int e0 = b * EPB;
    for (int i = t; i < EPB; i += 256) {
        int e = e0 + i;
        int src = ei[e], dst = ei[N_EDGES + e], cat = ea[e];
        int xs = x[src];
        int pos = atomicAdd(&curS[dst >> 7], 1);
        pmid[pos] = src | ((cat * NCAT + xs) << 16) | ((dst & 127) << 25);
    }
}

// ---------------- per-bucket finalize: exact CSR rows + in-bucket ordering -------------
__global__ __launch_bounds__(256) void k_final(
    const int* __restrict__ pmid, const int* __restrict__ tot,
    int* __restrict__ packed, int* __restrict__ row_start, int* __restrict__ row_end)
{
    __shared__ int bst[NBUCK + 1];
    __shared__ int part[256];
    __shared__ int cnt[BNODES];
    __shared__ int scan_s[BNODES];
    int b = blockIdx.x, t = threadIdx.x;
    build_bstart(tot, bst, part, t);
    int beg = bst[b], end = bst[b + 1];
    if (t < BNODES) cnt[t] = 0;
    __syncthreads();
    for (int e = beg + t; e < end; e += 256)
        atomicAdd(&cnt[((unsigned)pmid[e] >> 25) & 127], 1);
    __syncthreads();
    if (t < BNODES) scan_s[t] = cnt[t];
    __syncthreads();
    for (int off = 1; off < BNODES; off <<= 1) {
        int add = (t >= off && t < BNODES) ? scan_s[t - off] : 0;
        __syncthreads();
        if (t < BNODES) scan_s[t] += add;
        __syncthreads();
    }
    if (t < BNODES) {
        int c = cnt[t];
        int excl = scan_s[t] - c;          // exclusive within bucket
        int node = b * BNODES + t;
        if (node < N_NODES) {
            row_start[node] = beg + excl;
            row_end[node] = beg + excl + c;
        }
        cnt[t] = beg + excl;               // reuse as cursor
    }
    __syncthreads();
    for (int e = beg + t; e < end; e += 256) {
        int p = pmid[e];
        int pos = atomicAdd(&cnt[((unsigned)p >> 25) & 127], 1);
        packed[pos] = p & 0x1FFFFFF;       // src | catx<<16
    }
}

// per-edge load bundle
struct EdgeLd { uint4 kv; float4 t; };
__device__ __forceinline__ float edge_dot(const EdgeLd& e, const float4& q4) {
    float p;
    p = (__uint_as_float(e.kv.x & 0xFFFF0000u) + e.t.x) * q4.x;
    p = fmaf(__uint_as_float(e.kv.y & 0xFFFF0000u) + e.t.y, q4.y, p);
    p = fmaf(__uint_as_float(e.kv.z & 0xFFFF0000u) + e.t.z, q4.z, p);
    p = fmaf(__uint_as_float(e.kv.w & 0xFFFF0000u) + e.t.w, q4.w, p);
    return radd16(p) * SCALE;
}
__device__ __forceinline__ float4 edge_val(const EdgeLd& e) {
    float4 v;
    v.x = __uint_as_float(e.kv.x << 16) + e.t.x;
    v.y = __uint_as_float(e.kv.y << 16) + e.t.y;
    v.z = __uint_as_float(e.kv.z << 16) + e.t.z;
    v.w = __uint_as_float(e.kv.w << 16) + e.t.w;
    return v;
}

// ---------------- fused gather-attention + next-layer qkv GEMM epilogue --------------
// MODE 0: layer 0 — k/v/q from 42-entry global tables (L1-resident), epilogue gemm
// MODE 1: mid layer — global qkv in, epilogue gemm
// MODE 2: last layer — global qkv in, write fp32 h + gate
template<int MODE>
__device__ __forceinline__ void agg_body(
    const int* __restrict__ row_start, const int* __restrict__ row_end,
    const int* __restrict__ packed, const int* __restrict__ x,
    const unsigned* __restrict__ qs_in, const unsigned* __restrict__ kv_in,
    const unsigned* __restrict__ tqs, const unsigned* __restrict__ tkv,
    const float* __restrict__ te,
    const ushort_t* __restrict__ wbn, const float* __restrict__ bqn,
    const float* __restrict__ bkn, const float* __restrict__ bvn,
    const float* __restrict__ bsn,
    unsigned* __restrict__ qs_out, unsigned* __restrict__ kv_out,
    float* __restrict__ hf, const float* __restrict__ gW,
    const float* __restrict__ gb, float* __restrict__ gate,
    float* tel, ushort_t* hs16, int* pkl)
{
    int t = threadIdx.x, bid = blockIdx.x;
    int wave = t >> 6, lane = t & 63;
    int g = lane >> 4, i16 = lane & 15;
    int dst = bid * 16 + wave * 4 + g;
    int beg = row_start[dst], end = row_end[dst];
    int beg0 = row_start[bid * 16];
    int cnt = row_end[bid * 16 + 15] - beg0;
    bool use_lds = (cnt <= PKCAP);
    for (int i = t; i < 640; i += 256) tel[i] = te[i];
    if (use_lds) for (int i = t; i < cnt; i += 256) pkl[i] = packed[beg0 + i];
    uint4 uq;
    if constexpr (MODE == 0)
        uq = *(const uint4*)(tqs + (x[dst] << 6) + (i16 << 2));
    else
        uq = *(const uint4*)(qs_in + (size_t)dst * 64 + (i16 << 2));
    __syncthreads();
    float4 q4, s4;
    q4.x = __uint_as_float(uq.x << 16); s4.x = __uint_as_float(uq.x & 0xFFFF0000u);
    q4.y = __uint_as_float(uq.y << 16); s4.y = __uint_as_float(uq.y & 0xFFFF0000u);
    q4.z = __uint_as_float(uq.z << 16); s4.z = __uint_as_float(uq.z & 0xFFFF0000u);
    q4.w = __uint_as_float(uq.w << 16); s4.w = __uint_as_float(uq.w & 0xFFFF0000u);
    float m = -1e30f, l = 0.f;
    float4 acc = {0.f, 0.f, 0.f, 0.f};

    auto eload = [&](int pkt) {
        EdgeLd r;
        unsigned catx = ((unsigned)pkt >> 16) & 0x1FFu;
        int cat = (int)((catx * 1561u) >> 16);        // catx / 42
        r.t = *(const float4*)(tel + (cat << 6) + (i16 << 2));
        if constexpr (MODE == 0) {
            int xc = (int)catx - cat * NCAT;
            r.kv = *(const uint4*)(tkv + (xc << 6) + (i16 << 2));
        } else {
            int src = pkt & 0xFFFF;
            r.kv = *(const uint4*)(kv_in + ((size_t)src << 6) + (i16 << 2));
        }
        return r;
    };
    auto run = [&](auto PKT) {
        int e = beg;
        for (; e + 3 < end; e += 4) {
            int p0 = PKT(e), p1 = PKT(e + 1), p2 = PKT(e + 2), p3 = PKT(e + 3);
            EdgeLd e0 = eload(p0), e1 = eload(p1), e2 = eload(p2), e3 = eload(p3);
            float a0 = edge_dot(e0, q4), a1 = edge_dot(e1, q4);
            float a2 = edge_dot(e2, q4), a3 = edge_dot(e3, q4);
            float mn = fmaxf(m, fmaxf(fmaxf(a0, a1), fmaxf(a2, a3)));
            float corr = __expf(m - mn);
            float w0 = __expf(a0 - mn), w1 = __expf(a1 - mn);
            float w2 = __expf(a2 - mn), w3 = __expf(a3 - mn);
            float4 v0 = edge_val(e0), v1 = edge_val(e1), v2 = edge_val(e2), v3 = edge_val(e3);
            acc.x = fmaf(w0, v0.x, fmaf(w1, v1.x, fmaf(w2, v2.x, fmaf(w3, v3.x, acc.x * corr))));
            acc.y = fmaf(w0, v0.y, fmaf(w1, v1.y, fmaf(w2, v2.y, fmaf(w3, v3.y, acc.y * corr))));
            acc.z = fmaf(w0, v0.z, fmaf(w1, v1.z, fmaf(w2, v2.z, fmaf(w3, v3.z, acc.z * corr))));
            acc.w = fmaf(w0, v0.w, fmaf(w1, v1.w, fmaf(w2, v2.w, fmaf(w3, v3.w, acc.w * corr))));
            l = fmaf(l, corr, (w0 + w1) + (w2 + w3));
            m = mn;
        }
        for (; e < end; e++) {
            EdgeLd e0 = eload(PKT(e));
            float a = edge_dot(e0, q4);
            float mn = fmaxf(m, a);
            float corr = __expf(m - mn);
            float w = __expf(a - mn);
            float4 v4 = edge_val(e0);
            acc.x = fmaf(w, v4.x, acc.x * corr);
            acc.y = fmaf(w, v4.y, acc.y * corr);
            acc.z = fmaf(w, v4.z, acc.z * corr);
            acc.w = fmaf(w, v4.w, acc.w * corr);
            l = fmaf(l, corr, w);
            m = mn;
        }
    };
    if (use_lds) run([&](int e) { return pkl[e - beg0]; });
    else         run([&](int e) { return packed[e]; });

    float inv = (l > 0.f) ? 1.f / l : 0.f;
    float4 hv;
    hv.x = fmaxf(acc.x * inv + s4.x, 0.f);
    hv.y = fmaxf(acc.y * inv + s4.y, 0.f);
    hv.z = fmaxf(acc.z * inv + s4.z, 0.f);
    hv.w = fmaxf(acc.w * inv + s4.w, 0.f);
    if constexpr (MODE == 2) {
        *(float4*)(hf + (size_t)dst * H + (i16 << 2)) = hv;
        float4 g4 = *(const float4*)(gW + (i16 << 2));
        float p = hv.x * g4.x + hv.y * g4.y + hv.z * g4.z + hv.w * g4.w;
        p = radd16(p);
        if (i16 == 0) gate[dst] = p + gb[0];
    } else {
        // stage the block's 16 fresh h rows as bf16, then 8 MFMA/wave -> next qkv
        uint2 hp;
        hp.x = f2bf(hv.x) | (f2bf(hv.y) << 16);
        hp.y = f2bf(hv.z) | (f2bf(hv.w) << 16);
        *(uint2*)(hs16 + (((wave * 4 + g) << 6) + (i16 << 2))) = hp;
        __syncthreads();
        int n16 = lane & 15, quad = lane >> 4;
        f32x4 oacc[4];
        #pragma unroll
        for (int i = 0; i < 4; i++) oacc[i] = (f32x4){0.f, 0.f, 0.f, 0.f};
        #pragma unroll
        for (int kb = 0; kb < 2; kb++) {
            bf16x8 afr = *(const bf16x8*)(hs16 + ((n16 << 6) + kb * 32 + quad * 8));
            #pragma unroll
            for (int mat = 0; mat < 4; mat++) {
                int ct = mat * 4 + wave;
                const bf16x8* bp = (const bf16x8*)(wbn + (((kb * 4 + quad) << 11) + ((ct * 16 + n16) << 3)));
                oacc[mat] = __builtin_amdgcn_mfma_f32_16x16x32_bf16(afr, *bp, oacc[mat], 0, 0, 0);
            }
        }
        int col = (wave << 4) + n16;
        float bQ = bqn[col], bK = bkn[col], bV = bvn[col], bS = bsn[col];
        int nb = bid * 16 + quad * 4;
        #pragma unroll
        for (int r = 0; r < 4; r++) {
            qs_out[(size_t)(nb + r) * 64 + col] = f2bf(oacc[0][r] + bQ) | (f2bf(oacc[3][r] + bS) << 16);
            kv_out[(size_t)(nb + r) * 64 + col] = f2bf(oacc[2][r] + bV) | (f2bf(oacc[1][r] + bK) << 16);
        }
    }
}

__global__ __launch_bounds__(256, 6) void k_agg0(
    const int* __restrict__ row_start, const int* __restrict__ row_end,
    const int* __restrict__ packed, const int* __restrict__ x,
    const unsigned* __restrict__ tqs, const unsigned* __restrict__ tkv,
    const float* __restrict__ te,
    const ushort_t* __restrict__ wbn, const float* __restrict__ bqn,
    const float* __restrict__ bkn, const float* __restrict__ bvn,
    const float* __restrict__ bsn,
    unsigned* __restrict__ qs_out, unsigned* __restrict__ kv_out)
{
    __shared__ float tel[640];
    __shared__ ushort_t hs16[1024];
    __shared__ int pkl[PKCAP];
    agg_body<0>(row_start, row_end, packed, x, nullptr, nullptr, tqs, tkv, te,
                wbn, bqn, bkn, bvn, bsn, qs_out, kv_out,
                nullptr, nullptr, nullptr, nullptr, tel, hs16, pkl);
}

__global__ __launch_bounds__(256, 6) void k_agg1(
    const int* __restrict__ row_start, const int* __restrict__ row_end,
    const int* __restrict__ packed,
    const unsigned* __restrict__ qs_in, const unsigned* __restrict__ kv_in,
    const float* __restrict__ te,
    const ushort_t* __restrict__ wbn, const float* __restrict__ bqn,
    const float* __restrict__ bkn, const float* __restrict__ bvn,
    const float* __restrict__ bsn,
    unsigned* __restrict__ qs_out, unsigned* __restrict__ kv_out)
{
    __shared__ float tel[640];
    __shared__ ushort_t hs16[1024];
    __shared__ int pkl[PKCAP];
    agg_body<1>(row_start, row_end, packed, nullptr, qs_in, kv_in, nullptr, nullptr, te,
                wbn, bqn, bkn, bvn, bsn, qs_out, kv_out,
                nullptr, nullptr, nullptr, nullptr, tel, hs16, pkl);
}

// ---------------- agg layer 2 + fused per-graph readout via atomic countdown ----------
// After a tile's h/gate writes: release fence, decrement gcnt[g] for each graph g the
// tile intersects; the block seeing old==1 acquire-fences and runs g's readout inline.
// Non-blocking: no spin anywhere.
__global__ __launch_bounds__(256, 6) void k_agg2(
    const int* __restrict__ row_start, const int* __restrict__ row_end,
    const int* __restrict__ packed,
    const unsigned* __restrict__ qs_in, const unsigned* __restrict__ kv_in,
    const float* __restrict__ te,
    float* __restrict__ hf, const float* __restrict__ gW,
    const float* __restrict__ gb, float* __restrict__ gate,
    const int* __restrict__ batch, int* __restrict__ gcnt,
    const int* __restrict__ gs, const float* __restrict__ oW,
    const float* __restrict__ ob, float* __restrict__ out)
{
    __shared__ float tel[640];
    __shared__ int pkl[PKCAP];
    __shared__ float wls[H * OUTD];      // 8 KB, staged only in readout path
    __shared__ float hsr[8][H + 1];
    __shared__ float red[256];
    __shared__ float den_s[8];
    __shared__ float gmax_s, den_tot;
    __shared__ int sinfo[2];

    agg_body<2>(row_start, row_end, packed, nullptr, qs_in, kv_in, nullptr, nullptr, te,
                nullptr, nullptr, nullptr, nullptr, nullptr, nullptr, nullptr,
                hf, gW, gb, gate, tel, nullptr, pkl);

    int t = threadIdx.x;
    __syncthreads();
    if (t == 0) { sinfo[0] = batch[blockIdx.x * 16]; sinfo[1] = batch[blockIdx.x * 16 + 15]; }
    __syncthreads();
    int ga = sinfo[0], gb2 = sinfo[1];
    __builtin_amdgcn_fence(__ATOMIC_RELEASE, "agent");
    for (int g = ga; g <= gb2; ++g) {
        if (t == 0)
            sinfo[0] = __hip_atomic_fetch_add(&gcnt[g], -1, __ATOMIC_ACQ_REL,
                                              __HIP_MEMORY_SCOPE_AGENT);
        __syncthreads();
        bool last = (sinfo[0] == 1);
        __syncthreads();
        if (last) {
            __builtin_amdgcn_fence(__ATOMIC_ACQUIRE, "agent");
            // ---- inline readout for graph g (identical math to k_readout2) ----
            int ln = t >> 5, o = t & 31;
            for (int i = t; i < H * OUTD; i += 256) wls[i] = oW[i];
            int beg = gs[g], end = gs[g + 1];
            float mx = -INFINITY;
            for (int n = beg + t; n < end; n += 256) mx = fmaxf(mx, gate[n]);
            red[t] = mx;
            __syncthreads();
            for (int sft = 128; sft > 0; sft >>= 1) {
                if (t < sft) red[t] = fmaxf(red[t], red[t + sft]);
                __syncthreads();
            }
            if (t == 0) gmax_s = red[0];
            __syncthreads();
            float gm = gmax_s;
            float acc = 0.f, den = 0.f;
            for (int n0 = beg; n0 < end; n0 += 8) {
                __syncthreads();
                for (int i = t; i < 8 * H; i += 256) {
                    int r = i >> 6, c = i & 63;
                    int n = n0 + r;
                    hsr[r][c] = (n < end) ? hf[(size_t)n * H + c] : 0.f;
                }
                __syncthreads();
                int n = n0 + ln;
                if (n < end) {
                    float wt = __expf(gate[n] - gm);
                    float d0 = 0.f;
                    #pragma unroll
                    for (int i = 0; i < H; i++) d0 += hsr[ln][i] * wls[i * OUTD + o];
                    acc += wt * d0;
                    if (o == 0) den += wt;
                }
            }
            __syncthreads();
            red[t] = acc;
            if (o == 0) den_s[ln] = den;
            __syncthreads();
            for (int sft = 4; sft >= 1; sft >>= 1) {
                if (ln < sft) red[t] += red[t + sft * 32];
                __syncthreads();
            }
            if (t == 0) {
                float dt = 0.f;
                #pragma unroll
                for (int i = 0; i < 8; i++) dt += den_s[i];
                den_tot = dt;
            }
            __syncthreads();
            if (ln == 0) {
                float dt = den_tot;
                out[g * OUTD + o] = (dt > 0.f) ? red[o] / dt + ob[o] : 0.f;
            }
        }
        __syncthreads();
    }
}

extern "C" void kernel_launch(void* const* d_in, const int* in_sizes, int n_in,
                              void* d_out, int out_size, void* d_ws, size_t ws_size,
                              hipStream_t stream)
{
    const int* x        = (const int*)d_in[0];
    const int* ei       = (const int*)d_in[1];
    const int* ea       = (const int*)d_in[2];
    const int* batch    = (const int*)d_in[3];
    const float* node_emb = (const float*)d_in[4];
    const float* edge_emb = (const float*)d_in[5];
    const float* Wq    = (const float*)d_in[6];
    const float* Wk    = (const float*)d_in[7];
    const float* Wv    = (const float*)d_in[8];
    const float* We    = (const float*)d_in[9];
    const float* Wskip = (const float*)d_in[10];
    const float* bq    = (const float*)d_in[11];
    const float* bk    = (const float*)d_in[12];
    const float* bv    = (const float*)d_in[13];
    const float* bskip = (const float*)d_in[14];
    const float* gate_W = (const float*)d_in[15];
    const float* gate_b = (const float*)d_in[16];
    const float* out_W  = (const float*)d_in[17];
    const float* out_b  = (const float*)d_in[18];
    float* out = (float*)d_out;

    const size_t NH = (size_t)N_NODES * H;       // 3,200,000
    float* ws   = (float*)d_ws;
    unsigned* qs_a = (unsigned*)ws;              // layer-1 qkv (written by agg0)
    unsigned* kv_a = qs_a + NH;
    unsigned* qs_b = kv_a + NH;                  // layer-2 qkv (written by agg1)
    unsigned* kv_b = qs_b + NH;
    float* hf32 = (float*)(kv_b + NH);           // fp32 h (final layer only)
    float* te   = hf32 + NH;                     // LAYERS*10*64 = 1920
    float* gate = te + LAYERS * 10 * H;
    int* row_start = (int*)(gate + N_NODES);
    int* row_end   = row_start + N_NODES;
    int* packed    = row_end + N_NODES;          // final CSR edge packets
    int* pmid      = packed + N_EDGES;           // bucket-sorted intermediate
    int* hist      = pmid + N_EDGES;             // NBUCK * NB_HISTB ([bucket][block])
    int* tot       = hist + NBUCK * NB_HISTB;    // NBUCK bucket totals
    int* gs        = tot + NBUCK;                // 257 ints
    unsigned* tqs  = (unsigned*)(gs + NGRAPH + 1);   // 42*64 layer-0 q|s table
    unsigned* tkv  = tqs + FB_TAB * 64;              // 42*64 layer-0 v|k table
    ushort_t* wb16 = (ushort_t*)(tkv + FB_TAB * 64); // 3*16384 bf16 weights (chunk-major)
    int* gcnt      = (int*)(wb16 + 3 * 16384);       // NGRAPH tile-countdowns

    k_front<<<NB_FRONT, 256, 0, stream>>>(x, node_emb, edge_emb, We, te, ei, hist, batch,
                                          gs, gcnt, Wq, Wk, Wv, Wskip, bq, bk, bv, bskip,
                                          wb16, tqs, tkv);
    k_scan<<<NB_SCAN, 256, 0, stream>>>(hist, tot);
    k_scatter<<<NB_HISTB, 256, 0, stream>>>(ei, ea, x, hist, tot, pmid);
    k_final<<<NBUCK, 256, 0, stream>>>(pmid, tot, packed, row_start, row_end);

    // layer 0: table-based input, epilogue gemm (wb layer 1) -> A
    k_agg0<<<NB_AGG, 256, 0, stream>>>(
        row_start, row_end, packed, x, tqs, tkv, te,
        wb16 + (size_t)1 * 16384, bq + H, bk + H, bv + H, bskip + H, qs_a, kv_a);
    // layer 1: read A, epilogue gemm (wb layer 2) -> B
    k_agg1<<<NB_AGG, 256, 0, stream>>>(
        row_start, row_end, packed, qs_a, kv_a, te + 10 * H,
        wb16 + (size_t)2 * 16384, bq + 2 * H, bk + 2 * H, bv + 2 * H, bskip + 2 * H, qs_b, kv_b);
    // layer 2: read B, write fp32 h + gate, fused countdown readout
    k_agg2<<<NB_AGG, 256, 0, stream>>>(
        row_start, row_end, packed, qs_b, kv_b, te + 2 * 10 * H,
        hf32, gate_W, gate_b, gate, batch, gcnt, gs, out_W, out_b, out);
}

// Round 11
// 440.102 us; speedup vs baseline: 1.5314x; 1.5314x over previous
//
#include <hip/hip_runtime.h>
#include <hip/hip_bf16.h>

#define N_NODES 50000
#define N_EDGES 800000
#define H 64
#define ED 32
#define LAYERS 3
#define NGRAPH 256
#define OUTD 32
#define SCALE 0.125f
#define NCAT 42

// bucketed counting sort for CSR build (no global atomics anywhere)
#define BNODES 128                                  // nodes per bucket (dst >> 7)
#define NBUCK 391                                   // ceil(50000/128)
#define NB_HISTB 256                                // histogram / scatter blocks
#define EPB (N_EDGES / NB_HISTB)                    // 3125 edges per block

// fused front-end virtual block ranges
#define FB_HIST 256
#define FB_TE   8
#define FB_GB   2
#define FB_WB   192                                 // 3*16384 bf16 weight fragments / 256
#define FB_TAB  NCAT                                // layer-0 qkv table, 1 block per category
#define NB_FRONT (FB_HIST + FB_TE + FB_GB + FB_WB + FB_TAB)

#define NB_SCAN   98                                // 391 buckets / 4 per block
#define NB_AGG    3125                              // 50000 dsts / 16
#define PKCAP     768                               // staged packets per block (avg 256)

typedef __attribute__((ext_vector_type(8))) short bf16x8;
typedef __attribute__((ext_vector_type(4))) float f32x4;
typedef unsigned short ushort_t;

// fp32 -> bf16 round-to-nearest-even
__device__ __forceinline__ unsigned f2bf(float f) {
    unsigned u = __float_as_uint(f);
    return (u + 0x7FFFu + ((u >> 16) & 1u)) >> 16;
}

// 16-lane all-reduce sum via DPP (VALU only, no LDS pipe).
__device__ __forceinline__ float radd16(float x) {
    x += __int_as_float(__builtin_amdgcn_update_dpp(0, __float_as_int(x), 0xB1, 0xF, 0xF, true));   // quad_perm 1,0,3,2
    x += __int_as_float(__builtin_amdgcn_update_dpp(0, __float_as_int(x), 0x4E, 0xF, 0xF, true));   // quad_perm 2,3,0,1
    x += __int_as_float(__builtin_amdgcn_update_dpp(0, __float_as_int(x), 0x124, 0xF, 0xF, true));  // row_ror:4
    x += __int_as_float(__builtin_amdgcn_update_dpp(0, __float_as_int(x), 0x128, 0xF, 0xF, true));  // row_ror:8
    return x;
}

// shared prologue: exclusive scan of 391 bucket totals -> bst[] in LDS
__device__ __forceinline__ void build_bstart(const int* __restrict__ tot,
                                             int* bst, int* part, int t) {
    int u0 = t * 2, u1 = t * 2 + 1;
    int a0 = (u0 < NBUCK) ? tot[u0] : 0;
    int a1 = (u1 < NBUCK) ? tot[u1] : 0;
    part[t] = a0 + a1;
    __syncthreads();
    for (int off = 1; off < 256; off <<= 1) {
        int add = (t >= off) ? part[t - off] : 0;
        __syncthreads();
        part[t] += add;
        __syncthreads();
    }
    int excl = part[t] - (a0 + a1);
    if (u0 < NBUCK) bst[u0] = excl;
    if (u1 < NBUCK) bst[u1] = excl + a0;
    if (t == 0) bst[NBUCK] = N_EDGES;
    __syncthreads();
}

// ---------------- fused front end: hist | te | gbounds | weights | layer0-table --------
__global__ __launch_bounds__(256) void k_front(
    const int* __restrict__ x, const float* __restrict__ node_emb,
    const float* __restrict__ edge_emb, const float* __restrict__ We, float* __restrict__ te,
    const int* __restrict__ ei, int* __restrict__ hist,
    const int* __restrict__ batch, int* __restrict__ gs,
    const float* __restrict__ Wq, const float* __restrict__ Wk,
    const float* __restrict__ Wv, const float* __restrict__ Wsk,
    const float* __restrict__ bq, const float* __restrict__ bk,
    const float* __restrict__ bv, const float* __restrict__ bsk,
    ushort_t* __restrict__ wb16,
    unsigned* __restrict__ tqs, unsigned* __restrict__ tkv)
{
    __shared__ int lh[NBUCK];
    __shared__ float tb[4][64];
    int b = blockIdx.x, t = threadIdx.x;
    if (b < FB_HIST) {
        // per-block bucket histogram in LDS; transposed writeback hist[bucket][block]
        for (int i = t; i < NBUCK; i += 256) lh[i] = 0;
        __syncthreads();
        const int* dstp = ei + N_EDGES + b * EPB;
        for (int i = t; i < EPB; i += 256)
            atomicAdd(&lh[dstp[i] >> 7], 1);
        __syncthreads();
        for (int i = t; i < NBUCK; i += 256) hist[i * NB_HISTB + b] = lh[i];
    } else if (b < FB_HIST + FB_TE) {
        int i = (b - FB_HIST) * 256 + t;
        if (i < LAYERS * 10 * H) {
            int c = i & 63;
            int cat = (i >> 6) % 10;
            int l = i / (10 * H);
            float acc = 0.f;
            for (int d = 0; d < ED; d++)
                acc += edge_emb[cat * ED + d] * We[((size_t)l * ED + d) * H + c];
            te[i] = acc;
        }
    } else if (b < FB_HIST + FB_TE + FB_GB) {
        int g = (b - FB_HIST - FB_TE) * 256 + t;
        if (g <= NGRAPH) {
            int lo = 0, hi = N_NODES;
            while (lo < hi) {
                int mid = (lo + hi) >> 1;
                if (batch[mid] < g) lo = mid + 1; else hi = mid;
            }
            gs[g] = lo;
        }
    } else if (b < FB_HIST + FB_TE + FB_GB + FB_WB) {
        // chunk-major weight layout: wb16[l][c_id][r][j]  (c_id = kb*4+quad, r = ct*16+n16)
        int g = (b - FB_HIST - FB_TE - FB_GB) * 256 + t;   // < 49152
        int l = g >> 14;
        int rem = g & 16383;
        int c_id = rem >> 11;
        int rr = (rem >> 3) & 255;
        int j = rem & 7;
        int mat = rr >> 6, n = rr & 63;
        int k = ((c_id >> 2) << 5) + ((c_id & 3) << 3) + j;
        const float* Wm = (mat == 0) ? Wq : (mat == 1) ? Wk : (mat == 2) ? Wv : Wsk;
        wb16[g] = (ushort_t)f2bf(Wm[(size_t)l * 4096 + k * 64 + n]);
    } else {
        // layer-0 qkv table: one block per node category, fp32 matvec (exact)
        int cat = b - (FB_HIST + FB_TE + FB_GB + FB_WB);
        int mat = t >> 6, c = t & 63;
        const float* Wm = (mat == 0) ? Wq : (mat == 1) ? Wk : (mat == 2) ? Wv : Wsk;
        const float* bm = (mat == 0) ? bq : (mat == 1) ? bk : (mat == 2) ? bv : bsk;
        float acc = bm[c];
        for (int k = 0; k < H; k++)
            acc += node_emb[cat * H + k] * Wm[k * 64 + c];
        tb[mat][c] = acc;
        __syncthreads();
        if (t < 64) {
            tqs[cat * 64 + t] = f2bf(tb[0][t]) | (f2bf(tb[3][t]) << 16);   // q | skip
            tkv[cat * 64 + t] = f2bf(tb[2][t]) | (f2bf(tb[1][t]) << 16);   // v | k
        }
    }
}

// ---------------- per-bucket block-prefix scan (in-place) ----------------
__global__ __launch_bounds__(256) void k_scan(int* __restrict__ hist, int* __restrict__ tot)
{
    __shared__ int sv[256];
    int sb = blockIdx.x, t = threadIdx.x;
    for (int r = 0; r < 4; r++) {
        int u = sb * 4 + r;
        if (u < NBUCK) {
            int v = hist[u * NB_HISTB + t];
            sv[t] = v;
            __syncthreads();
            for (int off = 1; off < 256; off <<= 1) {
                int add = (t >= off) ? sv[t - off] : 0;
                __syncthreads();
                sv[t] += add;
                __syncthreads();
            }
            int incl = sv[t];
            hist[u * NB_HISTB + t] = incl - v;   // exclusive prefix, in place
            if (t == 255) tot[u] = incl;
            __syncthreads();
        }
    }
}

// ---------------- scatter: rank via LDS atomics against per-block cursors -------------
// packet: src(0..15) | catx(16..24) where catx = cat*42 + x[src] | (dst&127)(25..31)
__global__ __launch_bounds__(256) void k_scatter(
    const int* __restrict__ ei, const int* __restrict__ ea, const int* __restrict__ x,
    const int* __restrict__ hist, const int* __restrict__ tot,
    int* __restrict__ pmid)
{
    __shared__ int bst[NBUCK + 1];
    __shared__ int part[256];
    __shared__ int curS[NBUCK];
    int b = blockIdx.x, t = threadIdx.x;
    build_bstart(tot, bst, part, t);
    for (int u = t; u < NBUCK; u += 256)
        curS[u] = bst[u] + hist[u * NB_HISTB + b];
    __syncthreads();
    int e0 = b * EPB;
    for (int i = t; i < EPB; i += 256) {
        int e = e0 + i;
        int src = ei[e], dst = ei[N_EDGES + e], cat = ea[e];
        int xs = x[src];
        int pos = atomicAdd(&curS[dst >> 7], 1);
        pmid[pos] = src | ((cat * NCAT + xs) << 16) | ((dst & 127) << 25);
    }
}

// ---------------- per-bucket finalize: exact CSR rows + in-bucket ordering -------------
__global__ __launch_bounds__(256) void k_final(
    const int* __restrict__ pmid, const int* __restrict__ tot,
    int* __restrict__ packed, int* __restrict__ row_start, int* __restrict__ row_end)
{
    __shared__ int bst[NBUCK + 1];
    __shared__ int part[256];
    __shared__ int cnt[BNODES];
    __shared__ int scan_s[BNODES];
    int b = blockIdx.x, t = threadIdx.x;
    build_bstart(tot, bst, part, t);
    int beg = bst[b], end = bst[b + 1];
    if (t < BNODES) cnt[t] = 0;
    __syncthreads();
    for (int e = beg + t; e < end; e += 256)
        atomicAdd(&cnt[((unsigned)pmid[e] >> 25) & 127], 1);
    __syncthreads();
    if (t < BNODES) scan_s[t] = cnt[t];
    __syncthreads();
    for (int off = 1; off < BNODES; off <<= 1) {
        int add = (t >= off && t < BNODES) ? scan_s[t - off] : 0;
        __syncthreads();
        if (t < BNODES) scan_s[t] += add;
        __syncthreads();
    }
    if (t < BNODES) {
        int c = cnt[t];
        int excl = scan_s[t] - c;          // exclusive within bucket
        int node = b * BNODES + t;
        if (node < N_NODES) {
            row_start[node] = beg + excl;
            row_end[node] = beg + excl + c;
        }
        cnt[t] = beg + excl;               // reuse as cursor
    }
    __syncthreads();
    for (int e = beg + t; e < end; e += 256) {
        int p = pmid[e];
        int pos = atomicAdd(&cnt[((unsigned)p >> 25) & 127], 1);
        packed[pos] = p & 0x1FFFFFF;       // src | catx<<16
    }
}

// per-edge load bundle
struct EdgeLd { uint4 kv; float4 t; };
__device__ __forceinline__ float edge_dot(const EdgeLd& e, const float4& q4) {
    float p;
    p = (__uint_as_float(e.kv.x & 0xFFFF0000u) + e.t.x) * q4.x;
    p = fmaf(__uint_as_float(e.kv.y & 0xFFFF0000u) + e.t.y, q4.y, p);
    p = fmaf(__uint_as_float(e.kv.z & 0xFFFF0000u) + e.t.z, q4.z, p);
    p = fmaf(__uint_as_float(e.kv.w & 0xFFFF0000u) + e.t.w, q4.w, p);
    return radd16(p) * SCALE;
}
__device__ __forceinline__ float4 edge_val(const EdgeLd& e) {
    float4 v;
    v.x = __uint_as_float(e.kv.x << 16) + e.t.x;
    v.y = __uint_as_float(e.kv.y << 16) + e.t.y;
    v.z = __uint_as_float(e.kv.z << 16) + e.t.z;
    v.w = __uint_as_float(e.kv.w << 16) + e.t.w;
    return v;
}

// ---------------- fused gather-attention + next-layer qkv GEMM epilogue --------------
// MODE 0: layer 0 — k/v/q from 42-entry global tables (L1-resident), epilogue gemm
// MODE 1: mid layer — global qkv in, epilogue gemm
// MODE 2: last layer — global qkv in, write fp32 h + gate
// Inner loop: 2-stage software pipeline — prefetch next batch's kv rows (global,
// 300-600cy) while computing the current batch; te rows come from LDS at compute time.
template<int MODE>
__device__ __forceinline__ void agg_body(
    const int* __restrict__ row_start, const int* __restrict__ row_end,
    const int* __restrict__ packed, const int* __restrict__ x,
    const unsigned* __restrict__ qs_in, const unsigned* __restrict__ kv_in,
    const unsigned* __restrict__ tqs, const unsigned* __restrict__ tkv,
    const float* __restrict__ te,
    const ushort_t* __restrict__ wbn, const float* __restrict__ bqn,
    const float* __restrict__ bkn, const float* __restrict__ bvn,
    const float* __restrict__ bsn,
    unsigned* __restrict__ qs_out, unsigned* __restrict__ kv_out,
    float* __restrict__ hf, const float* __restrict__ gW,
    const float* __restrict__ gb, float* __restrict__ gate,
    float* tel, ushort_t* hs16, int* pkl)
{
    int t = threadIdx.x, bid = blockIdx.x;
    int wave = t >> 6, lane = t & 63;
    int g = lane >> 4, i16 = lane & 15;
    int dst = bid * 16 + wave * 4 + g;
    int beg = row_start[dst], end = row_end[dst];
    int beg0 = row_start[bid * 16];
    int cnt = row_end[bid * 16 + 15] - beg0;
    bool use_lds = (cnt <= PKCAP);
    for (int i = t; i < 640; i += 256) tel[i] = te[i];
    if (use_lds) for (int i = t; i < cnt; i += 256) pkl[i] = packed[beg0 + i];
    uint4 uq;
    if constexpr (MODE == 0)
        uq = *(const uint4*)(tqs + (x[dst] << 6) + (i16 << 2));
    else
        uq = *(const uint4*)(qs_in + (size_t)dst * 64 + (i16 << 2));
    __syncthreads();
    float4 q4, s4;
    q4.x = __uint_as_float(uq.x << 16); s4.x = __uint_as_float(uq.x & 0xFFFF0000u);
    q4.y = __uint_as_float(uq.y << 16); s4.y = __uint_as_float(uq.y & 0xFFFF0000u);
    q4.z = __uint_as_float(uq.z << 16); s4.z = __uint_as_float(uq.z & 0xFFFF0000u);
    q4.w = __uint_as_float(uq.w << 16); s4.w = __uint_as_float(uq.w & 0xFFFF0000u);
    float m = -1e30f, l = 0.f;
    float4 acc = {0.f, 0.f, 0.f, 0.f};

    auto kvload = [&](int pkt) -> uint4 {
        if constexpr (MODE == 0) {
            unsigned catx = ((unsigned)pkt >> 16) & 0x1FFu;
            int cat = (int)((catx * 1561u) >> 16);    // catx / 42
            int xc = (int)catx - cat * NCAT;
            return *(const uint4*)(tkv + (xc << 6) + (i16 << 2));
        } else {
            int src = pkt & 0xFFFF;
            return *(const uint4*)(kv_in + ((size_t)src << 6) + (i16 << 2));
        }
    };
    auto teload = [&](int pkt) -> float4 {
        unsigned catx = ((unsigned)pkt >> 16) & 0x1FFu;
        int cat = (int)((catx * 1561u) >> 16);        // catx / 42
        return *(const float4*)(tel + (cat << 6) + (i16 << 2));
    };
    auto step4 = [&](const EdgeLd& e0, const EdgeLd& e1, const EdgeLd& e2, const EdgeLd& e3) {
        float a0 = edge_dot(e0, q4), a1 = edge_dot(e1, q4);
        float a2 = edge_dot(e2, q4), a3 = edge_dot(e3, q4);
        float mn = fmaxf(m, fmaxf(fmaxf(a0, a1), fmaxf(a2, a3)));
        float corr = __expf(m - mn);
        float w0 = __expf(a0 - mn), w1 = __expf(a1 - mn);
        float w2 = __expf(a2 - mn), w3 = __expf(a3 - mn);
        float4 v0 = edge_val(e0), v1 = edge_val(e1), v2 = edge_val(e2), v3 = edge_val(e3);
        acc.x = fmaf(w0, v0.x, fmaf(w1, v1.x, fmaf(w2, v2.x, fmaf(w3, v3.x, acc.x * corr))));
        acc.y = fmaf(w0, v0.y, fmaf(w1, v1.y, fmaf(w2, v2.y, fmaf(w3, v3.y, acc.y * corr))));
        acc.z = fmaf(w0, v0.z, fmaf(w1, v1.z, fmaf(w2, v2.z, fmaf(w3, v3.z, acc.z * corr))));
        acc.w = fmaf(w0, v0.w, fmaf(w1, v1.w, fmaf(w2, v2.w, fmaf(w3, v3.w, acc.w * corr))));
        l = fmaf(l, corr, (w0 + w1) + (w2 + w3));
        m = mn;
    };
    auto run = [&](auto PKT) {
        int e = beg;
        int nfull = (end - beg) >> 2;
        if (nfull > 0) {
            int p0 = PKT(e), p1 = PKT(e + 1), p2 = PKT(e + 2), p3 = PKT(e + 3);
            uint4 k0 = kvload(p0), k1 = kvload(p1), k2 = kvload(p2), k3 = kvload(p3);
            e += 4;
            for (int bb = 1; bb <= nfull; ++bb) {
                int q0 = 0, q1 = 0, q2 = 0, q3 = 0;
                uint4 n0, n1, n2, n3;
                bool more = (bb < nfull);
                if (more) {
                    q0 = PKT(e); q1 = PKT(e + 1); q2 = PKT(e + 2); q3 = PKT(e + 3);
                    n0 = kvload(q0); n1 = kvload(q1); n2 = kvload(q2); n3 = kvload(q3);
                }
                EdgeLd e0 = {k0, teload(p0)}, e1 = {k1, teload(p1)};
                EdgeLd e2 = {k2, teload(p2)}, e3 = {k3, teload(p3)};
                step4(e0, e1, e2, e3);
                if (more) {
                    p0 = q0; p1 = q1; p2 = q2; p3 = q3;
                    k0 = n0; k1 = n1; k2 = n2; k3 = n3;
                    e += 4;
                }
            }
        }
        for (; e < end; e++) {
            int pkt = PKT(e);
            EdgeLd e0 = {kvload(pkt), teload(pkt)};
            float a = edge_dot(e0, q4);
            float mn = fmaxf(m, a);
            float corr = __expf(m - mn);
            float w = __expf(a - mn);
            float4 v4 = edge_val(e0);
            acc.x = fmaf(w, v4.x, acc.x * corr);
            acc.y = fmaf(w, v4.y, acc.y * corr);
            acc.z = fmaf(w, v4.z, acc.z * corr);
            acc.w = fmaf(w, v4.w, acc.w * corr);
            l = fmaf(l, corr, w);
            m = mn;
        }
    };
    if (use_lds) run([&](int e) { return pkl[e - beg0]; });
    else         run([&](int e) { return packed[e]; });

    float inv = (l > 0.f) ? 1.f / l : 0.f;
    float4 hv;
    hv.x = fmaxf(acc.x * inv + s4.x, 0.f);
    hv.y = fmaxf(acc.y * inv + s4.y, 0.f);
    hv.z = fmaxf(acc.z * inv + s4.z, 0.f);
    hv.w = fmaxf(acc.w * inv + s4.w, 0.f);
    if constexpr (MODE == 2) {
        *(float4*)(hf + (size_t)dst * H + (i16 << 2)) = hv;
        float4 g4 = *(const float4*)(gW + (i16 << 2));
        float p = hv.x * g4.x + hv.y * g4.y + hv.z * g4.z + hv.w * g4.w;
        p = radd16(p);
        if (i16 == 0) gate[dst] = p + gb[0];
    } else {
        // stage the block's 16 fresh h rows as bf16, then 8 MFMA/wave -> next qkv
        uint2 hp;
        hp.x = f2bf(hv.x) | (f2bf(hv.y) << 16);
        hp.y = f2bf(hv.z) | (f2bf(hv.w) << 16);
        *(uint2*)(hs16 + (((wave * 4 + g) << 6) + (i16 << 2))) = hp;
        __syncthreads();
        int n16 = lane & 15, quad = lane >> 4;
        f32x4 oacc[4];
        #pragma unroll
        for (int i = 0; i < 4; i++) oacc[i] = (f32x4){0.f, 0.f, 0.f, 0.f};
        #pragma unroll
        for (int kb = 0; kb < 2; kb++) {
            bf16x8 afr = *(const bf16x8*)(hs16 + ((n16 << 6) + kb * 32 + quad * 8));
            #pragma unroll
            for (int mat = 0; mat < 4; mat++) {
                int ct = mat * 4 + wave;
                const bf16x8* bp = (const bf16x8*)(wbn + (((kb * 4 + quad) << 11) + ((ct * 16 + n16) << 3)));
                oacc[mat] = __builtin_amdgcn_mfma_f32_16x16x32_bf16(afr, *bp, oacc[mat], 0, 0, 0);
            }
        }
        int col = (wave << 4) + n16;
        float bQ = bqn[col], bK = bkn[col], bV = bvn[col], bS = bsn[col];
        int nb = bid * 16 + quad * 4;
        #pragma unroll
        for (int r = 0; r < 4; r++) {
            qs_out[(size_t)(nb + r) * 64 + col] = f2bf(oacc[0][r] + bQ) | (f2bf(oacc[3][r] + bS) << 16);
            kv_out[(size_t)(nb + r) * 64 + col] = f2bf(oacc[2][r] + bV) | (f2bf(oacc[1][r] + bK) << 16);
        }
    }
}

__global__ __launch_bounds__(256, 6) void k_agg0(
    const int* __restrict__ row_start, const int* __restrict__ row_end,
    const int* __restrict__ packed, const int* __restrict__ x,
    const unsigned* __restrict__ tqs, const unsigned* __restrict__ tkv,
    const float* __restrict__ te,
    const ushort_t* __restrict__ wbn, const float* __restrict__ bqn,
    const float* __restrict__ bkn, const float* __restrict__ bvn,
    const float* __restrict__ bsn,
    unsigned* __restrict__ qs_out, unsigned* __restrict__ kv_out)
{
    __shared__ float tel[640];
    __shared__ ushort_t hs16[1024];
    __shared__ int pkl[PKCAP];
    agg_body<0>(row_start, row_end, packed, x, nullptr, nullptr, tqs, tkv, te,
                wbn, bqn, bkn, bvn, bsn, qs_out, kv_out,
                nullptr, nullptr, nullptr, nullptr, tel, hs16, pkl);
}

__global__ __launch_bounds__(256, 6) void k_agg1(
    const int* __restrict__ row_start, const int* __restrict__ row_end,
    const int* __restrict__ packed,
    const unsigned* __restrict__ qs_in, const unsigned* __restrict__ kv_in,
    const float* __restrict__ te,
    const ushort_t* __restrict__ wbn, const float* __restrict__ bqn,
    const float* __restrict__ bkn, const float* __restrict__ bvn,
    const float* __restrict__ bsn,
    unsigned* __restrict__ qs_out, unsigned* __restrict__ kv_out)
{
    __shared__ float tel[640];
    __shared__ ushort_t hs16[1024];
    __shared__ int pkl[PKCAP];
    agg_body<1>(row_start, row_end, packed, nullptr, qs_in, kv_in, nullptr, nullptr, te,
                wbn, bqn, bkn, bvn, bsn, qs_out, kv_out,
                nullptr, nullptr, nullptr, nullptr, tel, hs16, pkl);
}

__global__ __launch_bounds__(256, 6) void k_agg2(
    const int* __restrict__ row_start, const int* __restrict__ row_end,
    const int* __restrict__ packed,
    const unsigned* __restrict__ qs_in, const unsigned* __restrict__ kv_in,
    const float* __restrict__ te,
    float* __restrict__ hf, const float* __restrict__ gW,
    const float* __restrict__ gb, float* __restrict__ gate)
{
    __shared__ float tel[640];
    __shared__ int pkl[PKCAP];
    agg_body<2>(row_start, row_end, packed, nullptr, qs_in, kv_in, nullptr, nullptr, te,
                nullptr, nullptr, nullptr, nullptr, nullptr, nullptr, nullptr,
                hf, gW, gb, gate, tel, nullptr, pkl);
}

// ---------------- fused per-graph readout (W column in registers) ----------------
__global__ __launch_bounds__(256) void k_readout2(
    const float* __restrict__ h, const float* __restrict__ oW,
    const float* __restrict__ ob, const float* __restrict__ gate,
    const int* __restrict__ gs, float* __restrict__ out)
{
    __shared__ float hs[8][H + 1];
    __shared__ float red[256];
    __shared__ float den_s[8];
    __shared__ float gmax_s, den_tot;
    int t = threadIdx.x;
    int g = blockIdx.x;
    int ln = t >> 5, o = t & 31;
    float wreg[H];
    #pragma unroll
    for (int i = 0; i < H; i++) wreg[i] = oW[i * OUTD + o];
    int beg = gs[g], end = gs[g + 1];
    float mx = -INFINITY;
    for (int n = beg + t; n < end; n += 256) mx = fmaxf(mx, gate[n]);
    red[t] = mx;
    __syncthreads();
    for (int sft = 128; sft > 0; sft >>= 1) {
        if (t < sft) red[t] = fmaxf(red[t], red[t + sft]);
        __syncthreads();
    }
    if (t == 0) gmax_s = red[0];
    __syncthreads();
    float gm = gmax_s;
    float acc = 0.f, den = 0.f;
    for (int n0 = beg; n0 < end; n0 += 8) {
        __syncthreads();
        for (int i = t; i < 8 * H; i += 256) {
            int r = i >> 6, c = i & 63;
            int n = n0 + r;
            hs[r][c] = (n < end) ? h[(size_t)n * H + c] : 0.f;
        }
        __syncthreads();
        int n = n0 + ln;
        if (n < end) {
            float wt = __expf(gate[n] - gm);
            float d0 = 0.f;
            #pragma unroll
            for (int i = 0; i < H; i++) d0 += hs[ln][i] * wreg[i];
            acc += wt * d0;
            if (o == 0) den += wt;
        }
    }
    __syncthreads();
    red[t] = acc;
    if (o == 0) den_s[ln] = den;
    __syncthreads();
    for (int sft = 4; sft >= 1; sft >>= 1) {
        if (ln < sft) red[t] += red[t + sft * 32];
        __syncthreads();
    }
    if (t == 0) {
        float dt = 0.f;
        #pragma unroll
        for (int i = 0; i < 8; i++) dt += den_s[i];
        den_tot = dt;
    }
    __syncthreads();
    if (ln == 0) {
        float dt = den_tot;
        out[g * OUTD + o] = (dt > 0.f) ? red[o] / dt + ob[o] : 0.f;
    }
}

extern "C" void kernel_launch(void* const* d_in, const int* in_sizes, int n_in,
                              void* d_out, int out_size, void* d_ws, size_t ws_size,
                              hipStream_t stream)
{
    const int* x        = (const int*)d_in[0];
    const int* ei       = (const int*)d_in[1];
    const int* ea       = (const int*)d_in[2];
    const int* batch    = (const int*)d_in[3];
    const float* node_emb = (const float*)d_in[4];
    const float* edge_emb = (const float*)d_in[5];
    const float* Wq    = (const float*)d_in[6];
    const float* Wk    = (const float*)d_in[7];
    const float* Wv    = (const float*)d_in[8];
    const float* We    = (const float*)d_in[9];
    const float* Wskip = (const float*)d_in[10];
    const float* bq    = (const float*)d_in[11];
    const float* bk    = (const float*)d_in[12];
    const float* bv    = (const float*)d_in[13];
    const float* bskip = (const float*)d_in[14];
    const float* gate_W = (const float*)d_in[15];
    const float* gate_b = (const float*)d_in[16];
    const float* out_W  = (const float*)d_in[17];
    const float* out_b  = (const float*)d_in[18];
    float* out = (float*)d_out;

    const size_t NH = (size_t)N_NODES * H;       // 3,200,000
    float* ws   = (float*)d_ws;
    unsigned* qs_a = (unsigned*)ws;              // layer-1 qkv (written by agg0)
    unsigned* kv_a = qs_a + NH;
    unsigned* qs_b = kv_a + NH;                  // layer-2 qkv (written by agg1)
    unsigned* kv_b = qs_b + NH;
    float* hf32 = (float*)(kv_b + NH);           // fp32 h (final layer only)
    float* te   = hf32 + NH;                     // LAYERS*10*64 = 1920
    float* gate = te + LAYERS * 10 * H;
    int* row_start = (int*)(gate + N_NODES);
    int* row_end   = row_start + N_NODES;
    int* packed    = row_end + N_NODES;          // final CSR edge packets
    int* pmid      = packed + N_EDGES;           // bucket-sorted intermediate
    int* hist      = pmid + N_EDGES;             // NBUCK * NB_HISTB ([bucket][block])
    int* tot       = hist + NBUCK * NB_HISTB;    // NBUCK bucket totals
    int* gs        = tot + NBUCK;                // 257 ints
    unsigned* tqs  = (unsigned*)(gs + NGRAPH + 1);   // 42*64 layer-0 q|s table
    unsigned* tkv  = tqs + FB_TAB * 64;              // 42*64 layer-0 v|k table
    ushort_t* wb16 = (ushort_t*)(tkv + FB_TAB * 64); // 3*16384 bf16 weights (chunk-major)

    k_front<<<NB_FRONT, 256, 0, stream>>>(x, node_emb, edge_emb, We, te, ei, hist, batch, gs,
                                          Wq, Wk, Wv, Wskip, bq, bk, bv, bskip, wb16, tqs, tkv);
    k_scan<<<NB_SCAN, 256, 0, stream>>>(hist, tot);
    k_scatter<<<NB_HISTB, 256, 0, stream>>>(ei, ea, x, hist, tot, pmid);
    k_final<<<NBUCK, 256, 0, stream>>>(pmid, tot, packed, row_start, row_end);

    // layer 0: table-based input, epilogue gemm (wb layer 1) -> A
    k_agg0<<<NB_AGG, 256, 0, stream>>>(
        row_start, row_end, packed, x, tqs, tkv, te,
        wb16 + (size_t)1 * 16384, bq + H, bk + H, bv + H, bskip + H, qs_a, kv_a);
    // layer 1: read A, epilogue gemm (wb layer 2) -> B
    k_agg1<<<NB_AGG, 256, 0, stream>>>(
        row_start, row_end, packed, qs_a, kv_a, te + 10 * H,
        wb16 + (size_t)2 * 16384, bq + 2 * H, bk + 2 * H, bv + 2 * H, bskip + 2 * H, qs_b, kv_b);
    // layer 2: read B, write fp32 h + gate
    k_agg2<<<NB_AGG, 256, 0, stream>>>(
        row_start, row_end, packed, qs_b, kv_b, te + 2 * 10 * H,
        hf32, gate_W, gate_b, gate);

    k_readout2<<<NGRAPH, 256, 0, stream>>>(hf32, out_W, out_b, gate, gs, out);
}

// Round 12
// 258.379 us; speedup vs baseline: 2.6085x; 1.7033x over previous
//
#include <hip/hip_runtime.h>
#include <hip/hip_bf16.h>

#define N_NODES 50000
#define N_EDGES 800000
#define H 64
#define ED 32
#define LAYERS 3
#define NGRAPH 256
#define OUTD 32
#define SCALE 0.125f
#define NCAT 42

// bucketed counting sort for CSR build (no global atomics anywhere)
#define BNODES 128                                  // nodes per bucket (dst >> 7)
#define NBUCK 391                                   // ceil(50000/128)
#define NB_HISTB 256                                // histogram / scatter blocks
#define EPB (N_EDGES / NB_HISTB)                    // 3125 edges per block

// fused front-end virtual block ranges
#define FB_HIST 256
#define FB_TE   8
#define FB_GB   2
#define FB_WB   192                                 // 3*16384 bf16 weight fragments / 256
#define FB_TAB  NCAT                                // layer-0 qkv table, 1 block per category
#define NB_FRONT (FB_HIST + FB_TE + FB_GB + FB_WB + FB_TAB)

#define NB_SCAN   98                                // 391 buckets / 4 per block
#define NB_AGG    3125                              // 50000 dsts / 16
#define PKCAP     768                               // staged packets per block (avg 256)

typedef __attribute__((ext_vector_type(8))) short bf16x8;
typedef __attribute__((ext_vector_type(4))) float f32x4;
typedef unsigned short ushort_t;

// fp32 -> bf16 round-to-nearest-even
__device__ __forceinline__ unsigned f2bf(float f) {
    unsigned u = __float_as_uint(f);
    return (u + 0x7FFFu + ((u >> 16) & 1u)) >> 16;
}

// 16-lane all-reduce sum via DPP (VALU only, no LDS pipe).
__device__ __forceinline__ float radd16(float x) {
    x += __int_as_float(__builtin_amdgcn_update_dpp(0, __float_as_int(x), 0xB1, 0xF, 0xF, true));   // quad_perm 1,0,3,2
    x += __int_as_float(__builtin_amdgcn_update_dpp(0, __float_as_int(x), 0x4E, 0xF, 0xF, true));   // quad_perm 2,3,0,1
    x += __int_as_float(__builtin_amdgcn_update_dpp(0, __float_as_int(x), 0x124, 0xF, 0xF, true));  // row_ror:4
    x += __int_as_float(__builtin_amdgcn_update_dpp(0, __float_as_int(x), 0x128, 0xF, 0xF, true));  // row_ror:8
    return x;
}

// shared prologue: exclusive scan of 391 bucket totals -> bst[] in LDS
__device__ __forceinline__ void build_bstart(const int* __restrict__ tot,
                                             int* bst, int* part, int t) {
    int u0 = t * 2, u1 = t * 2 + 1;
    int a0 = (u0 < NBUCK) ? tot[u0] : 0;
    int a1 = (u1 < NBUCK) ? tot[u1] : 0;
    part[t] = a0 + a1;
    __syncthreads();
    for (int off = 1; off < 256; off <<= 1) {
        int add = (t >= off) ? part[t - off] : 0;
        __syncthreads();
        part[t] += add;
        __syncthreads();
    }
    int excl = part[t] - (a0 + a1);
    if (u0 < NBUCK) bst[u0] = excl;
    if (u1 < NBUCK) bst[u1] = excl + a0;
    if (t == 0) bst[NBUCK] = N_EDGES;
    __syncthreads();
}

// ---------------- fused front end: hist | te | gbounds | weights | layer0-table --------
__global__ __launch_bounds__(256) void k_front(
    const int* __restrict__ x, const float* __restrict__ node_emb,
    const float* __restrict__ edge_emb, const float* __restrict__ We, float* __restrict__ te,
    const int* __restrict__ ei, int* __restrict__ hist,
    const int* __restrict__ batch, int* __restrict__ gs,
    const float* __restrict__ Wq, const float* __restrict__ Wk,
    const float* __restrict__ Wv, const float* __restrict__ Wsk,
    const float* __restrict__ bq, const float* __restrict__ bk,
    const float* __restrict__ bv, const float* __restrict__ bsk,
    ushort_t* __restrict__ wb16,
    unsigned* __restrict__ tqs, unsigned* __restrict__ tkv)
{
    __shared__ int lh[NBUCK];
    __shared__ float tb[4][64];
    int b = blockIdx.x, t = threadIdx.x;
    if (b < FB_HIST) {
        // per-block bucket histogram in LDS; transposed writeback hist[bucket][block]
        for (int i = t; i < NBUCK; i += 256) lh[i] = 0;
        __syncthreads();
        const int* dstp = ei + N_EDGES + b * EPB;
        for (int i = t; i < EPB; i += 256)
            atomicAdd(&lh[dstp[i] >> 7], 1);
        __syncthreads();
        for (int i = t; i < NBUCK; i += 256) hist[i * NB_HISTB + b] = lh[i];
    } else if (b < FB_HIST + FB_TE) {
        int i = (b - FB_HIST) * 256 + t;
        if (i < LAYERS * 10 * H) {
            int c = i & 63;
            int cat = (i >> 6) % 10;
            int l = i / (10 * H);
            float acc = 0.f;
            for (int d = 0; d < ED; d++)
                acc += edge_emb[cat * ED + d] * We[((size_t)l * ED + d) * H + c];
            te[i] = acc;
        }
    } else if (b < FB_HIST + FB_TE + FB_GB) {
        int g = (b - FB_HIST - FB_TE) * 256 + t;
        if (g <= NGRAPH) {
            int lo = 0, hi = N_NODES;
            while (lo < hi) {
                int mid = (lo + hi) >> 1;
                if (batch[mid] < g) lo = mid + 1; else hi = mid;
            }
            gs[g] = lo;
        }
    } else if (b < FB_HIST + FB_TE + FB_GB + FB_WB) {
        // chunk-major weight layout: wb16[l][c_id][r][j]  (c_id = kb*4+quad, r = ct*16+n16)
        int g = (b - FB_HIST - FB_TE - FB_GB) * 256 + t;   // < 49152
        int l = g >> 14;
        int rem = g & 16383;
        int c_id = rem >> 11;
        int rr = (rem >> 3) & 255;
        int j = rem & 7;
        int mat = rr >> 6, n = rr & 63;
        int k = ((c_id >> 2) << 5) + ((c_id & 3) << 3) + j;
        const float* Wm = (mat == 0) ? Wq : (mat == 1) ? Wk : (mat == 2) ? Wv : Wsk;
        wb16[g] = (ushort_t)f2bf(Wm[(size_t)l * 4096 + k * 64 + n]);
    } else {
        // layer-0 qkv table: one block per node category, fp32 matvec (exact)
        int cat = b - (FB_HIST + FB_TE + FB_GB + FB_WB);
        int mat = t >> 6, c = t & 63;
        const float* Wm = (mat == 0) ? Wq : (mat == 1) ? Wk : (mat == 2) ? Wv : Wsk;
        const float* bm = (mat == 0) ? bq : (mat == 1) ? bk : (mat == 2) ? bv : bsk;
        float acc = bm[c];
        for (int k = 0; k < H; k++)
            acc += node_emb[cat * H + k] * Wm[k * 64 + c];
        tb[mat][c] = acc;
        __syncthreads();
        if (t < 64) {
            tqs[cat * 64 + t] = f2bf(tb[0][t]) | (f2bf(tb[3][t]) << 16);   // q | skip
            tkv[cat * 64 + t] = f2bf(tb[2][t]) | (f2bf(tb[1][t]) << 16);   // v | k
        }
    }
}

// ---------------- per-bucket block-prefix scan (in-place) ----------------
__global__ __launch_bounds__(256) void k_scan(int* __restrict__ hist, int* __restrict__ tot)
{
    __shared__ int sv[256];
    int sb = blockIdx.x, t = threadIdx.x;
    for (int r = 0; r < 4; r++) {
        int u = sb * 4 + r;
        if (u < NBUCK) {
            int v = hist[u * NB_HISTB + t];
            sv[t] = v;
            __syncthreads();
            for (int off = 1; off < 256; off <<= 1) {
                int add = (t >= off) ? sv[t - off] : 0;
                __syncthreads();
                sv[t] += add;
                __syncthreads();
            }
            int incl = sv[t];
            hist[u * NB_HISTB + t] = incl - v;   // exclusive prefix, in place
            if (t == 255) tot[u] = incl;
            __syncthreads();
        }
    }
}

// ---------------- scatter: rank via LDS atomics against per-block cursors -------------
// packet: src(0..15) | catx(16..24) where catx = cat*42 + x[src] | (dst&127)(25..31)
__global__ __launch_bounds__(256) void k_scatter(
    const int* __restrict__ ei, const int* __restrict__ ea, const int* __restrict__ x,
    const int* __restrict__ hist, const int* __restrict__ tot,
    int* __restrict__ pmid)
{
    __shared__ int bst[NBUCK + 1];
    __shared__ int part[256];
    __shared__ int curS[NBUCK];
    int b = blockIdx.x, t = threadIdx.x;
    build_bstart(tot, bst, part, t);
    for (int u = t; u < NBUCK; u += 256)
        curS[u] = bst[u] + hist[u * NB_HISTB + b];
    __syncthreads();
    int e0 = b * EPB;
    for (int i = t; i < EPB; i += 256) {
        int e = e0 + i;
        int src = ei[e], dst = ei[N_EDGES + e], cat = ea[e];
        int xs = x[src];
        int pos = atomicAdd(&curS[dst >> 7], 1);
        pmid[pos] = src | ((cat * NCAT + xs) << 16) | ((dst & 127) << 25);
    }
}

// ---------------- per-bucket finalize: exact CSR rows + in-bucket ordering -------------
__global__ __launch_bounds__(256) void k_final(
    const int* __restrict__ pmid, const int* __restrict__ tot,
    int* __restrict__ packed, int* __restrict__ row_start, int* __restrict__ row_end)
{
    __shared__ int bst[NBUCK + 1];
    __shared__ int part[256];
    __shared__ int cnt[BNODES];
    __shared__ int scan_s[BNODES];
    int b = blockIdx.x, t = threadIdx.x;
    build_bstart(tot, bst, part, t);
    int beg = bst[b], end = bst[b + 1];
    if (t < BNODES) cnt[t] = 0;
    __syncthreads();
    for (int e = beg + t; e < end; e += 256)
        atomicAdd(&cnt[((unsigned)pmid[e] >> 25) & 127], 1);
    __syncthreads();
    if (t < BNODES) scan_s[t] = cnt[t];
    __syncthreads();
    for (int off = 1; off < BNODES; off <<= 1) {
        int add = (t >= off && t < BNODES) ? scan_s[t - off] : 0;
        __syncthreads();
        if (t < BNODES) scan_s[t] += add;
        __syncthreads();
    }
    if (t < BNODES) {
        int c = cnt[t];
        int excl = scan_s[t] - c;          // exclusive within bucket
        int node = b * BNODES + t;
        if (node < N_NODES) {
            row_start[node] = beg + excl;
            row_end[node] = beg + excl + c;
        }
        cnt[t] = beg + excl;               // reuse as cursor
    }
    __syncthreads();
    for (int e = beg + t; e < end; e += 256) {
        int p = pmid[e];
        int pos = atomicAdd(&cnt[((unsigned)p >> 25) & 127], 1);
        packed[pos] = p & 0x1FFFFFF;       // src | catx<<16
    }
}

// per-edge load bundle
struct EdgeLd { uint4 kv; float4 t; };
__device__ __forceinline__ float edge_dot(const EdgeLd& e, const float4& q4) {
    float p;
    p = (__uint_as_float(e.kv.x & 0xFFFF0000u) + e.t.x) * q4.x;
    p = fmaf(__uint_as_float(e.kv.y & 0xFFFF0000u) + e.t.y, q4.y, p);
    p = fmaf(__uint_as_float(e.kv.z & 0xFFFF0000u) + e.t.z, q4.z, p);
    p = fmaf(__uint_as_float(e.kv.w & 0xFFFF0000u) + e.t.w, q4.w, p);
    return radd16(p) * SCALE;
}
__device__ __forceinline__ float4 edge_val(const EdgeLd& e) {
    float4 v;
    v.x = __uint_as_float(e.kv.x << 16) + e.t.x;
    v.y = __uint_as_float(e.kv.y << 16) + e.t.y;
    v.z = __uint_as_float(e.kv.z << 16) + e.t.z;
    v.w = __uint_as_float(e.kv.w << 16) + e.t.w;
    return v;
}

// ---------------- fused gather-attention + next-layer qkv GEMM epilogue --------------
// MODE 0: layer 0 — k/v/q from 42-entry global tables (L1-resident), epilogue gemm
// MODE 1: mid layer — global qkv in, epilogue gemm
// MODE 2: last layer — global qkv in, write fp32 h + gate
template<int MODE>
__device__ __forceinline__ void agg_body(
    const int* __restrict__ row_start, const int* __restrict__ row_end,
    const int* __restrict__ packed, const int* __restrict__ x,
    const unsigned* __restrict__ qs_in, const unsigned* __restrict__ kv_in,
    const unsigned* __restrict__ tqs, const unsigned* __restrict__ tkv,
    const float* __restrict__ te,
    const ushort_t* __restrict__ wbn, const float* __restrict__ bqn,
    const float* __restrict__ bkn, const float* __restrict__ bvn,
    const float* __restrict__ bsn,
    unsigned* __restrict__ qs_out, unsigned* __restrict__ kv_out,
    float* __restrict__ hf, const float* __restrict__ gW,
    const float* __restrict__ gb, float* __restrict__ gate,
    float* tel, ushort_t* hs16, int* pkl)
{
    int t = threadIdx.x, bid = blockIdx.x;
    int wave = t >> 6, lane = t & 63;
    int g = lane >> 4, i16 = lane & 15;
    int dst = bid * 16 + wave * 4 + g;
    int beg = row_start[dst], end = row_end[dst];
    int beg0 = row_start[bid * 16];
    int cnt = row_end[bid * 16 + 15] - beg0;
    bool use_lds = (cnt <= PKCAP);
    for (int i = t; i < 640; i += 256) tel[i] = te[i];
    if (use_lds) for (int i = t; i < cnt; i += 256) pkl[i] = packed[beg0 + i];
    uint4 uq;
    if constexpr (MODE == 0)
        uq = *(const uint4*)(tqs + (x[dst] << 6) + (i16 << 2));
    else
        uq = *(const uint4*)(qs_in + (size_t)dst * 64 + (i16 << 2));
    __syncthreads();
    float4 q4, s4;
    q4.x = __uint_as_float(uq.x << 16); s4.x = __uint_as_float(uq.x & 0xFFFF0000u);
    q4.y = __uint_as_float(uq.y << 16); s4.y = __uint_as_float(uq.y & 0xFFFF0000u);
    q4.z = __uint_as_float(uq.z << 16); s4.z = __uint_as_float(uq.z & 0xFFFF0000u);
    q4.w = __uint_as_float(uq.w << 16); s4.w = __uint_as_float(uq.w & 0xFFFF0000u);
    float m = -1e30f, l = 0.f;
    float4 acc = {0.f, 0.f, 0.f, 0.f};

    auto eload = [&](int pkt) {
        EdgeLd r;
        unsigned catx = ((unsigned)pkt >> 16) & 0x1FFu;
        int cat = (int)((catx * 1561u) >> 16);        // catx / 42
        r.t = *(const float4*)(tel + (cat << 6) + (i16 << 2));
        if constexpr (MODE == 0) {
            int xc = (int)catx - cat * NCAT;
            r.kv = *(const uint4*)(tkv + (xc << 6) + (i16 << 2));
        } else {
            int src = pkt & 0xFFFF;
            r.kv = *(const uint4*)(kv_in + ((size_t)src << 6) + (i16 << 2));
        }
        return r;
    };
    auto run = [&](auto PKT) {
        int e = beg;
        for (; e + 3 < end; e += 4) {
            int p0 = PKT(e), p1 = PKT(e + 1), p2 = PKT(e + 2), p3 = PKT(e + 3);
            EdgeLd e0 = eload(p0), e1 = eload(p1), e2 = eload(p2), e3 = eload(p3);
            float a0 = edge_dot(e0, q4), a1 = edge_dot(e1, q4);
            float a2 = edge_dot(e2, q4), a3 = edge_dot(e3, q4);
            float mn = fmaxf(m, fmaxf(fmaxf(a0, a1), fmaxf(a2, a3)));
            float corr = __expf(m - mn);
            float w0 = __expf(a0 - mn), w1 = __expf(a1 - mn);
            float w2 = __expf(a2 - mn), w3 = __expf(a3 - mn);
            float4 v0 = edge_val(e0), v1 = edge_val(e1), v2 = edge_val(e2), v3 = edge_val(e3);
            acc.x = fmaf(w0, v0.x, fmaf(w1, v1.x, fmaf(w2, v2.x, fmaf(w3, v3.x, acc.x * corr))));
            acc.y = fmaf(w0, v0.y, fmaf(w1, v1.y, fmaf(w2, v2.y, fmaf(w3, v3.y, acc.y * corr))));
            acc.z = fmaf(w0, v0.z, fmaf(w1, v1.z, fmaf(w2, v2.z, fmaf(w3, v3.z, acc.z * corr))));
            acc.w = fmaf(w0, v0.w, fmaf(w1, v1.w, fmaf(w2, v2.w, fmaf(w3, v3.w, acc.w * corr))));
            l = fmaf(l, corr, (w0 + w1) + (w2 + w3));
            m = mn;
        }
        for (; e < end; e++) {
            EdgeLd e0 = eload(PKT(e));
            float a = edge_dot(e0, q4);
            float mn = fmaxf(m, a);
            float corr = __expf(m - mn);
            float w = __expf(a - mn);
            float4 v4 = edge_val(e0);
            acc.x = fmaf(w, v4.x, acc.x * corr);
            acc.y = fmaf(w, v4.y, acc.y * corr);
            acc.z = fmaf(w, v4.z, acc.z * corr);
            acc.w = fmaf(w, v4.w, acc.w * corr);
            l = fmaf(l, corr, w);
            m = mn;
        }
    };
    if (use_lds) run([&](int e) { return pkl[e - beg0]; });
    else         run([&](int e) { return packed[e]; });

    float inv = (l > 0.f) ? 1.f / l : 0.f;
    float4 hv;
    hv.x = fmaxf(acc.x * inv + s4.x, 0.f);
    hv.y = fmaxf(acc.y * inv + s4.y, 0.f);
    hv.z = fmaxf(acc.z * inv + s4.z, 0.f);
    hv.w = fmaxf(acc.w * inv + s4.w, 0.f);
    if constexpr (MODE == 2) {
        *(float4*)(hf + (size_t)dst * H + (i16 << 2)) = hv;
        float4 g4 = *(const float4*)(gW + (i16 << 2));
        float p = hv.x * g4.x + hv.y * g4.y + hv.z * g4.z + hv.w * g4.w;
        p = radd16(p);
        if (i16 == 0) gate[dst] = p + gb[0];
    } else {
        // stage the block's 16 fresh h rows as bf16, then 8 MFMA/wave -> next qkv
        uint2 hp;
        hp.x = f2bf(hv.x) | (f2bf(hv.y) << 16);
        hp.y = f2bf(hv.z) | (f2bf(hv.w) << 16);
        *(uint2*)(hs16 + (((wave * 4 + g) << 6) + (i16 << 2))) = hp;
        __syncthreads();
        int n16 = lane & 15, quad = lane >> 4;
        f32x4 oacc[4];
        #pragma unroll
        for (int i = 0; i < 4; i++) oacc[i] = (f32x4){0.f, 0.f, 0.f, 0.f};
        #pragma unroll
        for (int kb = 0; kb < 2; kb++) {
            bf16x8 afr = *(const bf16x8*)(hs16 + ((n16 << 6) + kb * 32 + quad * 8));
            #pragma unroll
            for (int mat = 0; mat < 4; mat++) {
                int ct = mat * 4 + wave;
                const bf16x8* bp = (const bf16x8*)(wbn + (((kb * 4 + quad) << 11) + ((ct * 16 + n16) << 3)));
                oacc[mat] = __builtin_amdgcn_mfma_f32_16x16x32_bf16(afr, *bp, oacc[mat], 0, 0, 0);
            }
        }
        int col = (wave << 4) + n16;
        float bQ = bqn[col], bK = bkn[col], bV = bvn[col], bS = bsn[col];
        int nb = bid * 16 + quad * 4;
        #pragma unroll
        for (int r = 0; r < 4; r++) {
            qs_out[(size_t)(nb + r) * 64 + col] = f2bf(oacc[0][r] + bQ) | (f2bf(oacc[3][r] + bS) << 16);
            kv_out[(size_t)(nb + r) * 64 + col] = f2bf(oacc[2][r] + bV) | (f2bf(oacc[1][r] + bK) << 16);
        }
    }
}

__global__ __launch_bounds__(256, 6) void k_agg0(
    const int* __restrict__ row_start, const int* __restrict__ row_end,
    const int* __restrict__ packed, const int* __restrict__ x,
    const unsigned* __restrict__ tqs, const unsigned* __restrict__ tkv,
    const float* __restrict__ te,
    const ushort_t* __restrict__ wbn, const float* __restrict__ bqn,
    const float* __restrict__ bkn, const float* __restrict__ bvn,
    const float* __restrict__ bsn,
    unsigned* __restrict__ qs_out, unsigned* __restrict__ kv_out)
{
    __shared__ float tel[640];
    __shared__ ushort_t hs16[1024];
    __shared__ int pkl[PKCAP];
    agg_body<0>(row_start, row_end, packed, x, nullptr, nullptr, tqs, tkv, te,
                wbn, bqn, bkn, bvn, bsn, qs_out, kv_out,
                nullptr, nullptr, nullptr, nullptr, tel, hs16, pkl);
}

__global__ __launch_bounds__(256, 6) void k_agg1(
    const int* __restrict__ row_start, const int* __restrict__ row_end,
    const int* __restrict__ packed,
    const unsigned* __restrict__ qs_in, const unsigned* __restrict__ kv_in,
    const float* __restrict__ te,
    const ushort_t* __restrict__ wbn, const float* __restrict__ bqn,
    const float* __restrict__ bkn, const float* __restrict__ bvn,
    const float* __restrict__ bsn,
    unsigned* __restrict__ qs_out, unsigned* __restrict__ kv_out)
{
    __shared__ float tel[640];
    __shared__ ushort_t hs16[1024];
    __shared__ int pkl[PKCAP];
    agg_body<1>(row_start, row_end, packed, nullptr, qs_in, kv_in, nullptr, nullptr, te,
                wbn, bqn, bkn, bvn, bsn, qs_out, kv_out,
                nullptr, nullptr, nullptr, nullptr, tel, hs16, pkl);
}

__global__ __launch_bounds__(256, 6) void k_agg2(
    const int* __restrict__ row_start, const int* __restrict__ row_end,
    const int* __restrict__ packed,
    const unsigned* __restrict__ qs_in, const unsigned* __restrict__ kv_in,
    const float* __restrict__ te,
    float* __restrict__ hf, const float* __restrict__ gW,
    const float* __restrict__ gb, float* __restrict__ gate)
{
    __shared__ float tel[640];
    __shared__ int pkl[PKCAP];
    agg_body<2>(row_start, row_end, packed, nullptr, qs_in, kv_in, nullptr, nullptr, te,
                nullptr, nullptr, nullptr, nullptr, nullptr, nullptr, nullptr,
                hf, gW, gb, gate, tel, nullptr, pkl);
}

// ---------------- fused per-graph readout (W column in registers) ----------------
__global__ __launch_bounds__(256) void k_readout2(
    const float* __restrict__ h, const float* __restrict__ oW,
    const float* __restrict__ ob, const float* __restrict__ gate,
    const int* __restrict__ gs, float* __restrict__ out)
{
    __shared__ float hs[8][H + 1];
    __shared__ float red[256];
    __shared__ float den_s[8];
    __shared__ float gmax_s, den_tot;
    int t = threadIdx.x;
    int g = blockIdx.x;
    int ln = t >> 5, o = t & 31;
    float wreg[H];
    #pragma unroll
    for (int i = 0; i < H; i++) wreg[i] = oW[i * OUTD + o];
    int beg = gs[g], end = gs[g + 1];
    float mx = -INFINITY;
    for (int n = beg + t; n < end; n += 256) mx = fmaxf(mx, gate[n]);
    red[t] = mx;
    __syncthreads();
    for (int sft = 128; sft > 0; sft >>= 1) {
        if (t < sft) red[t] = fmaxf(red[t], red[t + sft]);
        __syncthreads();
    }
    if (t == 0) gmax_s = red[0];
    __syncthreads();
    float gm = gmax_s;
    float acc = 0.f, den = 0.f;
    for (int n0 = beg; n0 < end; n0 += 8) {
        __syncthreads();
        for (int i = t; i < 8 * H; i += 256) {
            int r = i >> 6, c = i & 63;
            int n = n0 + r;
            hs[r][c] = (n < end) ? h[(size_t)n * H + c] : 0.f;
        }
        __syncthreads();
        int n = n0 + ln;
        if (n < end) {
            float wt = __expf(gate[n] - gm);
            float d0 = 0.f;
            #pragma unroll
            for (int i = 0; i < H; i++) d0 += hs[ln][i] * wreg[i];
            acc += wt * d0;
            if (o == 0) den += wt;
        }
    }
    __syncthreads();
    red[t] = acc;
    if (o == 0) den_s[ln] = den;
    __syncthreads();
    for (int sft = 4; sft >= 1; sft >>= 1) {
        if (ln < sft) red[t] += red[t + sft * 32];
        __syncthreads();
    }
    if (t == 0) {
        float dt = 0.f;
        #pragma unroll
        for (int i = 0; i < 8; i++) dt += den_s[i];
        den_tot = dt;
    }
    __syncthreads();
    if (ln == 0) {
        float dt = den_tot;
        out[g * OUTD + o] = (dt > 0.f) ? red[o] / dt + ob[o] : 0.f;
    }
}

extern "C" void kernel_launch(void* const* d_in, const int* in_sizes, int n_in,
                              void* d_out, int out_size, void* d_ws, size_t ws_size,
                              hipStream_t stream)
{
    const int* x        = (const int*)d_in[0];
    const int* ei       = (const int*)d_in[1];
    const int* ea       = (const int*)d_in[2];
    const int* batch    = (const int*)d_in[3];
    const float* node_emb = (const float*)d_in[4];
    const float* edge_emb = (const float*)d_in[5];
    const float* Wq    = (const float*)d_in[6];
    const float* Wk    = (const float*)d_in[7];
    const float* Wv    = (const float*)d_in[8];
    const float* We    = (const float*)d_in[9];
    const float* Wskip = (const float*)d_in[10];
    const float* bq    = (const float*)d_in[11];
    const float* bk    = (const float*)d_in[12];
    const float* bv    = (const float*)d_in[13];
    const float* bskip = (const float*)d_in[14];
    const float* gate_W = (const float*)d_in[15];
    const float* gate_b = (const float*)d_in[16];
    const float* out_W  = (const float*)d_in[17];
    const float* out_b  = (const float*)d_in[18];
    float* out = (float*)d_out;

    const size_t NH = (size_t)N_NODES * H;       // 3,200,000
    float* ws   = (float*)d_ws;
    unsigned* qs_a = (unsigned*)ws;              // layer-1 qkv (written by agg0)
    unsigned* kv_a = qs_a + NH;
    unsigned* qs_b = kv_a + NH;                  // layer-2 qkv (written by agg1)
    unsigned* kv_b = qs_b + NH;
    float* hf32 = (float*)(kv_b + NH);           // fp32 h (final layer only)
    float* te   = hf32 + NH;                     // LAYERS*10*64 = 1920
    float* gate = te + LAYERS * 10 * H;
    int* row_start = (int*)(gate + N_NODES);
    int* row_end   = row_start + N_NODES;
    int* packed    = row_end + N_NODES;          // final CSR edge packets
    int* pmid      = packed + N_EDGES;           // bucket-sorted intermediate
    int* hist      = pmid + N_EDGES;             // NBUCK * NB_HISTB ([bucket][block])
    int* tot       = hist + NBUCK * NB_HISTB;    // NBUCK bucket totals
    int* gs        = tot + NBUCK;                // 257 ints
    unsigned* tqs  = (unsigned*)(gs + NGRAPH + 1);   // 42*64 layer-0 q|s table
    unsigned* tkv  = tqs + FB_TAB * 64;              // 42*64 layer-0 v|k table
    ushort_t* wb16 = (ushort_t*)(tkv + FB_TAB * 64); // 3*16384 bf16 weights (chunk-major)

    k_front<<<NB_FRONT, 256, 0, stream>>>(x, node_emb, edge_emb, We, te, ei, hist, batch, gs,
                                          Wq, Wk, Wv, Wskip, bq, bk, bv, bskip, wb16, tqs, tkv);
    k_scan<<<NB_SCAN, 256, 0, stream>>>(hist, tot);
    k_scatter<<<NB_HISTB, 256, 0, stream>>>(ei, ea, x, hist, tot, pmid);
    k_final<<<NBUCK, 256, 0, stream>>>(pmid, tot, packed, row_start, row_end);

    // layer 0: table-based input, epilogue gemm (wb layer 1) -> A
    k_agg0<<<NB_AGG, 256, 0, stream>>>(
        row_start, row_end, packed, x, tqs, tkv, te,
        wb16 + (size_t)1 * 16384, bq + H, bk + H, bv + H, bskip + H, qs_a, kv_a);
    // layer 1: read A, epilogue gemm (wb layer 2) -> B
    k_agg1<<<NB_AGG, 256, 0, stream>>>(
        row_start, row_end, packed, qs_a, kv_a, te + 10 * H,
        wb16 + (size_t)2 * 16384, bq + 2 * H, bk + 2 * H, bv + 2 * H, bskip + 2 * H, qs_b, kv_b);
    // layer 2: read B, write fp32 h + gate
    k_agg2<<<NB_AGG, 256, 0, stream>>>(
        row_start, row_end, packed, qs_b, kv_b, te + 2 * 10 * H,
        hf32, gate_W, gate_b, gate);

    k_readout2<<<NGRAPH, 256, 0, stream>>>(hf32, out_W, out_b, gate, gs, out);
}